// Round 6
// baseline (264.308 us; speedup 1.0000x reference)
//
#include <hip/hip_runtime.h>
#include <math.h>

#define B_TOT   1024
#define S_DIM   64
#define N_DIM   256
#define UNFOLDS 12
#define EPSF    1e-8f
#define L2E     1.4426950408889634f
#define KMAX    192   // max padded live-count per column; Bin(256,0.5) never near this

// Guaranteed-native transcendentals.
#if defined(__has_builtin)
#  if __has_builtin(__builtin_amdgcn_exp2f)
#    define FEXP2(x) __builtin_amdgcn_exp2f(x)
#  endif
#  if __has_builtin(__builtin_amdgcn_rcpf)
#    define FRCP(x) __builtin_amdgcn_rcpf(x)
#  endif
#endif
#ifndef FEXP2
__device__ __forceinline__ float __fexp2_asm(float x){ float r; asm("v_exp_f32 %0, %1" : "=v"(r) : "v"(x)); return r; }
#  define FEXP2(x) __fexp2_asm(x)
#endif
#ifndef FRCP
__device__ __forceinline__ float __frcp_asm(float x){ float r; asm("v_rcp_f32 %0, %1" : "=v"(r) : "v"(x)); return r; }
#  define FRCP(x) __frcp_asm(x)
#endif

__device__ __forceinline__ float softplus_f(float x) {
    return log1pf(expf(x));
}

// Pack per-(pre,post) params as float4 {A, B, WE, WEr}, i-major / j-contiguous:
//   sigmoid(sigma*(v-mu)) = 1/(1+exp2(A*v+B)), A=-L2E*sigma, B=L2E*sigma*mu
//   WE = softplus(w)*mask, WEr = WE*erev.  WE > 0  <=>  mask == 1.
__global__ void ltc_precompute(const float* __restrict__ gleak, const float* __restrict__ vleak,
                               const float* __restrict__ cm,    const float* __restrict__ w,
                               const float* __restrict__ sigma, const float* __restrict__ mu,
                               const float* __restrict__ erev,
                               const float* __restrict__ sw,    const float* __restrict__ ssig,
                               const float* __restrict__ smu,   const float* __restrict__ serev,
                               const float* __restrict__ mask,  const float* __restrict__ smask,
                               float4* __restrict__ p4, float4* __restrict__ s4,
                               float4* __restrict__ pj)
{
    const int idx = blockIdx.x * blockDim.x + threadIdx.x;
    if (idx < N_DIM * N_DIM) {
        float we = softplus_f(w[idx]) * mask[idx];
        float sg = sigma[idx];
        float4 o;
        o.x = -L2E * sg;
        o.y =  L2E * sg * mu[idx];
        o.z =  we;
        o.w =  we * erev[idx];
        p4[idx] = o;
    }
    if (idx < S_DIM * N_DIM) {
        float we = softplus_f(sw[idx]) * smask[idx];
        float sg = ssig[idx];
        float4 o;
        o.x = -L2E * sg;
        o.y =  L2E * sg * smu[idx];
        o.z =  we;
        o.w =  we * serev[idx];
        s4[idx] = o;
    }
    if (idx < N_DIM) {
        float g = softplus_f(gleak[idx]);
        float4 o;
        o.x = softplus_f(cm[idx]) * (float)UNFOLDS;  // cm_t
        o.y = g;
        o.z = g * vleak[idx];
        o.w = 0.0f;
        pj[idx] = o;
    }
}

// Compact each column j to its live (mask==1) rows. k-major layout [k][j] so
// main-kernel loads stay coalesced. Pad to a multiple of 4 with zero-weight
// entries (contribute exactly 0). 1 block x 256 threads; trivial runtime.
__global__ void ltc_compact(const float4* __restrict__ p4,
                            float4* __restrict__ pc, unsigned short* __restrict__ pidx,
                            int* __restrict__ cnt4)
{
    const int j = threadIdx.x;
    int k = 0;
    for (int i = 0; i < N_DIM; ++i) {
        float4 p = p4[i * N_DIM + j];
        if (p.z > 0.0f && k < KMAX) {
            pc[k * N_DIM + j] = p;
            pidx[k * N_DIM + j] = (unsigned short)i;
            ++k;
        }
    }
    while ((k & 3) && k < KMAX) {
        pc[k * N_DIM + j] = make_float4(0.f, 0.f, 0.f, 0.f);
        pidx[k * N_DIM + j] = 0;
        ++k;
    }
    cnt4[j] = k >> 2;
}

// 1024 threads/block, 256 blocks, 4 batches each. j = tid&255, q = tid>>8
// (0..3); q-group strides the compacted list k = 4t+q, t < cnt4[j].
// v-read is an LDS gather (sorted indices -> bounded bank conflicts).
// All locals named scalars/float4 — no indexed arrays (R3: scratch spill).
__global__ __launch_bounds__(1024, 2)
void ltc_main(const float* __restrict__ inputs, const float* __restrict__ state,
              const float4* __restrict__ pc, const unsigned short* __restrict__ pidx,
              const int* __restrict__ cnt4,
              const float4* __restrict__ s4, const float4* __restrict__ pj,
              float* __restrict__ out)
{
    __shared__ float4 v4[N_DIM];        // v[i], component = batch
    __shared__ float4 pnum[4][N_DIM];   // partials [q][j]
    __shared__ float4 pden[4][N_DIM];
    __shared__ float  in_lds[4][S_DIM];

    const int tid = threadIdx.x;
    const int j   = tid & (N_DIM - 1);
    const int q   = tid >> 8;
    const int b0  = blockIdx.x << 2;

    ((float*)v4)[(j << 2) + q] = state[(b0 + q) * N_DIM + j];
    if (tid < 4 * S_DIM) in_lds[tid >> 6][tid & 63] = inputs[b0 * S_DIM + tid];

    const float4 c = pj[j];
    const float cmt = c.x, gl = c.y, glv = c.z;
    const float cg  = cmt + gl + EPSF;
    const int   myc = cnt4[j];
    __syncthreads();

    // ---- sensory pass: q covers s in [16q, 16q+16) ----
    float n0 = 0.f, n1 = 0.f, n2 = 0.f, n3 = 0.f;
    float d0 = 0.f, d1 = 0.f, d2 = 0.f, d3 = 0.f;
    {
        const float4* __restrict__ sr = s4 + (q << 4) * N_DIM + j;
        const int sbase = q << 4;
        #pragma unroll 4
        for (int s = 0; s < 16; ++s) {
            const float4 p = sr[s * N_DIM];
            float e0 = FEXP2(fmaf(p.x, in_lds[0][sbase + s], p.y));
            float e1 = FEXP2(fmaf(p.x, in_lds[1][sbase + s], p.y));
            float e2 = FEXP2(fmaf(p.x, in_lds[2][sbase + s], p.y));
            float e3 = FEXP2(fmaf(p.x, in_lds[3][sbase + s], p.y));
            float r0 = FRCP(1.0f + e0);
            float r1 = FRCP(1.0f + e1);
            float r2 = FRCP(1.0f + e2);
            float r3 = FRCP(1.0f + e3);
            n0 = fmaf(p.w, r0, n0); d0 = fmaf(p.z, r0, d0);
            n1 = fmaf(p.w, r1, n1); d1 = fmaf(p.z, r1, d1);
            n2 = fmaf(p.w, r2, n2); d2 = fmaf(p.z, r2, d2);
            n3 = fmaf(p.w, r3, n3); d3 = fmaf(p.z, r3, d3);
        }
    }
    pnum[q][j] = make_float4(n0, n1, n2, n3);
    pden[q][j] = make_float4(d0, d1, d2, d3);
    __syncthreads();

    // all threads redundantly reduce sensory partials into registers
    float4 sn = make_float4(0.f, 0.f, 0.f, 0.f);
    float4 sd = make_float4(0.f, 0.f, 0.f, 0.f);
    #pragma unroll
    for (int qq = 0; qq < 4; ++qq) {
        const float4 a = pnum[qq][j], b = pden[qq][j];
        sn.x += a.x; sn.y += a.y; sn.z += a.z; sn.w += a.w;
        sd.x += b.x; sd.y += b.y; sd.z += b.z; sd.w += b.w;
    }
    __syncthreads();   // pnum/pden reused below

    // ---- 12 ODE unfolds over the compacted list ----
    const float4*         __restrict__ pr0 = pc   + q * N_DIM + j;
    const unsigned short* __restrict__ ir0 = pidx + q * N_DIM + j;

    #pragma unroll 1
    for (int step = 0; step < UNFOLDS; ++step) {
        float m0 = 0.f, m1 = 0.f, m2 = 0.f, m3 = 0.f;
        float e0_ = 0.f, e1_ = 0.f, e2_ = 0.f, e3_ = 0.f;   // den accumulators

        const float4*         __restrict__ pp = pr0;
        const unsigned short* __restrict__ pi = ir0;
        #pragma unroll 2
        for (int t = 0; t < myc; ++t) {
            const float4 p  = *pp;
            const int    ii = *pi;
            pp += 4 * N_DIM;  pi += 4 * N_DIM;
            const float4 vv = v4[ii];          // LDS gather (sorted idx)
            float e0 = FEXP2(fmaf(p.x, vv.x, p.y));
            float e1 = FEXP2(fmaf(p.x, vv.y, p.y));
            float e2 = FEXP2(fmaf(p.x, vv.z, p.y));
            float e3 = FEXP2(fmaf(p.x, vv.w, p.y));
            float r0 = FRCP(1.0f + e0);
            float r1 = FRCP(1.0f + e1);
            float r2 = FRCP(1.0f + e2);
            float r3 = FRCP(1.0f + e3);
            m0 = fmaf(p.w, r0, m0); e0_ = fmaf(p.z, r0, e0_);
            m1 = fmaf(p.w, r1, m1); e1_ = fmaf(p.z, r1, e1_);
            m2 = fmaf(p.w, r2, m2); e2_ = fmaf(p.z, r2, e2_);
            m3 = fmaf(p.w, r3, m3); e3_ = fmaf(p.z, r3, e3_);
        }

        const float4 vo = v4[j];   // read old v BEFORE the barrier
        pnum[q][j] = make_float4(m0, m1, m2, m3);
        pden[q][j] = make_float4(e0_, e1_, e2_, e3_);
        __syncthreads();

        // redundant combine in all q-groups (bitwise-identical results)
        float4 tn = sn, td = sd;
        #pragma unroll
        for (int qq = 0; qq < 4; ++qq) {
            const float4 a = pnum[qq][j], b = pden[qq][j];
            tn.x += a.x; tn.y += a.y; tn.z += a.z; tn.w += a.w;
            td.x += b.x; td.y += b.y; td.z += b.z; td.w += b.w;
        }
        float4 vn;
        vn.x = (fmaf(cmt, vo.x, glv) + tn.x) * FRCP(cg + td.x);
        vn.y = (fmaf(cmt, vo.y, glv) + tn.y) * FRCP(cg + td.y);
        vn.z = (fmaf(cmt, vo.z, glv) + tn.z) * FRCP(cg + td.z);
        vn.w = (fmaf(cmt, vo.w, glv) + tn.w) * FRCP(cg + td.w);
        v4[j] = vn;                // 4 writers, identical bits — benign
        __syncthreads();
    }

    out[(b0 + q) * N_DIM + j] = ((const float*)v4)[(j << 2) + q];
}

extern "C" void kernel_launch(void* const* d_in, const int* in_sizes, int n_in,
                              void* d_out, int out_size, void* d_ws, size_t ws_size,
                              hipStream_t stream)
{
    const float* inputs = (const float*)d_in[0];
    const float* state  = (const float*)d_in[1];
    const float* gleak  = (const float*)d_in[2];
    const float* vleak  = (const float*)d_in[3];
    const float* cm     = (const float*)d_in[4];
    const float* w      = (const float*)d_in[5];
    const float* sigma  = (const float*)d_in[6];
    const float* mu     = (const float*)d_in[7];
    const float* erev   = (const float*)d_in[8];
    const float* sw     = (const float*)d_in[9];
    const float* ssig   = (const float*)d_in[10];
    const float* smu    = (const float*)d_in[11];
    const float* serev  = (const float*)d_in[12];
    const float* mask   = (const float*)d_in[13];
    const float* smask  = (const float*)d_in[14];

    float4* p4 = (float4*)d_ws;                        // [N*N]     = 1 MiB
    float4* s4 = p4 + N_DIM * N_DIM;                   // [S*N]     = 256 KiB
    float4* pc = s4 + S_DIM * N_DIM;                   // [KMAX*N]  = 768 KiB
    float4* pj = pc + KMAX * N_DIM;                    // [N]       = 4 KiB
    unsigned short* pidx = (unsigned short*)(pj + N_DIM);  // [KMAX*N] = 96 KiB
    int* cnt4 = (int*)(pidx + KMAX * N_DIM);           // [N]       = 1 KiB

    ltc_precompute<<<(N_DIM * N_DIM + 255) / 256, 256, 0, stream>>>(
        gleak, vleak, cm, w, sigma, mu, erev, sw, ssig, smu, serev, mask, smask,
        p4, s4, pj);

    ltc_compact<<<1, N_DIM, 0, stream>>>(p4, pc, pidx, cnt4);

    ltc_main<<<B_TOT / 4, 1024, 0, stream>>>(inputs, state, pc, pidx, cnt4,
                                             s4, pj, (float*)d_out);
}

// Round 7
// 164.201 us; speedup vs baseline: 1.6097x; 1.6097x over previous
//
#include <hip/hip_runtime.h>
#include <math.h>

#define B_TOT   1024
#define S_DIM   64
#define N_DIM   256
#define UNFOLDS 12
#define EPSF    1e-8f
#define L2E     1.4426950408889634f
#define KMAX    256   // full capacity: correct for any mask density

typedef unsigned short u16x8 __attribute__((ext_vector_type(8)));

// Guaranteed-native transcendentals.
#if defined(__has_builtin)
#  if __has_builtin(__builtin_amdgcn_exp2f)
#    define FEXP2(x) __builtin_amdgcn_exp2f(x)
#  endif
#  if __has_builtin(__builtin_amdgcn_rcpf)
#    define FRCP(x) __builtin_amdgcn_rcpf(x)
#  endif
#endif
#ifndef FEXP2
__device__ __forceinline__ float __fexp2_asm(float x){ float r; asm("v_exp_f32 %0, %1" : "=v"(r) : "v"(x)); return r; }
#  define FEXP2(x) __fexp2_asm(x)
#endif
#ifndef FRCP
__device__ __forceinline__ float __frcp_asm(float x){ float r; asm("v_rcp_f32 %0, %1" : "=v"(r) : "v"(x)); return r; }
#  define FRCP(x) __frcp_asm(x)
#endif

__device__ __forceinline__ float softplus_f(float x) {
    return log1pf(expf(x));
}

// Sensory params {A,B,WE,WEr} (s-major, j-contiguous), per-j combine constants,
// and umax reset.  sigmoid(sigma*(v-mu)) = 1/(1+exp2(A*v+B)).
__global__ void ltc_precompute_s(const float* __restrict__ gleak, const float* __restrict__ vleak,
                                 const float* __restrict__ cm,
                                 const float* __restrict__ sw,    const float* __restrict__ ssig,
                                 const float* __restrict__ smu,   const float* __restrict__ serev,
                                 const float* __restrict__ smask,
                                 float4* __restrict__ s4, float4* __restrict__ pj,
                                 int* __restrict__ umax)
{
    const int idx = blockIdx.x * blockDim.x + threadIdx.x;
    if (idx < S_DIM * N_DIM) {
        float we = softplus_f(sw[idx]) * smask[idx];
        float sg = ssig[idx];
        float4 o;
        o.x = -L2E * sg;
        o.y =  L2E * sg * smu[idx];
        o.z =  we;
        o.w =  we * serev[idx];
        s4[idx] = o;
    }
    if (idx < N_DIM) {
        float g = softplus_f(gleak[idx]);
        float4 o;
        o.x = softplus_f(cm[idx]) * (float)UNFOLDS;  // cm_t
        o.y = g;
        o.z = g * vleak[idx];
        o.w = 0.0f;
        pj[idx] = o;
    }
    if (idx == 0) *umax = 0;
}

// Fused precompute + parallel compaction. One block per column j; thread i
// computes the (i,j) param and a ballot prefix-scan compacts live rows.
// pc is k-major [k][j] (coalesced float4); pidxT is [j][KMAX] u16 holding
// PRE-SHIFTED byte offsets (i<<4) for the LDS gather. Zero-pad to KMAX.
__global__ __launch_bounds__(256)
void ltc_compact(const float* __restrict__ w,    const float* __restrict__ sigma,
                 const float* __restrict__ mu,   const float* __restrict__ erev,
                 const float* __restrict__ mask,
                 float4* __restrict__ pc, unsigned short* __restrict__ pidxT,
                 int* __restrict__ umax)
{
    const int j = blockIdx.x;
    const int i = threadIdx.x;
    const int idx = i * N_DIM + j;

    const float mk = mask[idx];
    const bool live = mk > 0.0f;
    float we = softplus_f(w[idx]) * mk;
    float sg = sigma[idx];
    float4 o;
    o.x = -L2E * sg;
    o.y =  L2E * sg * mu[idx];
    o.z =  we;
    o.w =  we * erev[idx];

    const int lane = i & 63, wv = i >> 6;
    const unsigned long long ball = __ballot(live);
    const int lpre = __popcll(ball & ((1ull << lane) - 1ull));
    __shared__ int wcnt[4];
    if (lane == 0) wcnt[wv] = __popcll(ball);
    __syncthreads();
    int base = 0;
    #pragma unroll
    for (int ww = 0; ww < 4; ++ww) base += (ww < wv) ? wcnt[ww] : 0;
    const int total = wcnt[0] + wcnt[1] + wcnt[2] + wcnt[3];

    if (live) {
        const int pos = base + lpre;
        pc[pos * N_DIM + j] = o;
        pidxT[j * KMAX + pos] = (unsigned short)(i << 4);
    }
    for (int k = total + i; k < KMAX; k += 256) {   // zero-pad (exact zeros)
        pc[k * N_DIM + j] = make_float4(0.f, 0.f, 0.f, 0.f);
        pidxT[j * KMAX + k] = 0;
    }
    if (i == 0) atomicMax(umax, total);
}

// One unrolled body: coalesced param load + LDS gather via pre-shifted byte
// offset + 4 sigmoids (native exp2/rcp) + 8 accum FMAs. Named locals only.
#define LTC_BODY(UU, OFF)                                                   \
    {                                                                       \
        const float4 p  = pr[(t + UU) * N_DIM];                             \
        const float4 vv = *(const float4*)((const char*)v4 + (int)(OFF));   \
        float e0 = FEXP2(fmaf(p.x, vv.x, p.y));                             \
        float e1 = FEXP2(fmaf(p.x, vv.y, p.y));                             \
        float e2 = FEXP2(fmaf(p.x, vv.z, p.y));                             \
        float e3 = FEXP2(fmaf(p.x, vv.w, p.y));                             \
        float r0 = FRCP(1.0f + e0);                                         \
        float r1 = FRCP(1.0f + e1);                                         \
        float r2 = FRCP(1.0f + e2);                                         \
        float r3 = FRCP(1.0f + e3);                                         \
        m0 = fmaf(p.w, r0, m0); d0 = fmaf(p.z, r0, d0);                     \
        m1 = fmaf(p.w, r1, m1); d1 = fmaf(p.z, r1, d1);                     \
        m2 = fmaf(p.w, r2, m2); d2 = fmaf(p.z, r2, d2);                     \
        m3 = fmaf(p.w, r3, m3); d3 = fmaf(p.z, r3, d3);                     \
    }

// 1024 threads/block, 256 blocks, 4 batches each. j = tid&255, q = tid>>8;
// q covers contiguous compacted k in [q*U4, (q+1)*U4), U4 = U/4, U uniform
// across all columns (multiple of 32) -> no divergence, unroll-8 with one
// ushort8 index load per 8 iterations.
__global__ __launch_bounds__(1024, 2)
void ltc_main(const float* __restrict__ inputs, const float* __restrict__ state,
              const float4* __restrict__ pc, const unsigned short* __restrict__ pidxT,
              const int* __restrict__ umax,
              const float4* __restrict__ s4, const float4* __restrict__ pj,
              float* __restrict__ out)
{
    __shared__ float4 v4[N_DIM];        // v[i], component = batch
    __shared__ float4 pnum[4][N_DIM];   // partials [q][j]
    __shared__ float4 pden[4][N_DIM];
    __shared__ float  in_lds[4][S_DIM];

    const int tid = threadIdx.x;
    const int j   = tid & (N_DIM - 1);
    const int q   = tid >> 8;
    const int b0  = blockIdx.x << 2;

    ((float*)v4)[(j << 2) + q] = state[(b0 + q) * N_DIM + j];
    if (tid < 4 * S_DIM) in_lds[tid >> 6][tid & 63] = inputs[b0 * S_DIM + tid];

    const float4 c = pj[j];
    const float cmt = c.x, gl = c.y, glv = c.z;
    const float cg  = cmt + gl + EPSF;

    const int Ucnt = *umax;                 // uniform scalar
    const int U    = (Ucnt + 31) & ~31;     // multiple of 32 (<= KMAX)
    const int U4   = U >> 2;                // per-q iters, multiple of 8
    __syncthreads();

    // ---- sensory pass: q covers s in [16q, 16q+16) ----
    float n0 = 0.f, n1 = 0.f, n2 = 0.f, n3 = 0.f;
    float d0s = 0.f, d1s = 0.f, d2s = 0.f, d3s = 0.f;
    {
        const float4* __restrict__ sr = s4 + (q << 4) * N_DIM + j;
        const int sbase = q << 4;
        #pragma unroll 4
        for (int s = 0; s < 16; ++s) {
            const float4 p = sr[s * N_DIM];
            float e0 = FEXP2(fmaf(p.x, in_lds[0][sbase + s], p.y));
            float e1 = FEXP2(fmaf(p.x, in_lds[1][sbase + s], p.y));
            float e2 = FEXP2(fmaf(p.x, in_lds[2][sbase + s], p.y));
            float e3 = FEXP2(fmaf(p.x, in_lds[3][sbase + s], p.y));
            float r0 = FRCP(1.0f + e0);
            float r1 = FRCP(1.0f + e1);
            float r2 = FRCP(1.0f + e2);
            float r3 = FRCP(1.0f + e3);
            n0 = fmaf(p.w, r0, n0); d0s = fmaf(p.z, r0, d0s);
            n1 = fmaf(p.w, r1, n1); d1s = fmaf(p.z, r1, d1s);
            n2 = fmaf(p.w, r2, n2); d2s = fmaf(p.z, r2, d2s);
            n3 = fmaf(p.w, r3, n3); d3s = fmaf(p.z, r3, d3s);
        }
    }
    pnum[q][j] = make_float4(n0, n1, n2, n3);
    pden[q][j] = make_float4(d0s, d1s, d2s, d3s);
    __syncthreads();

    // all threads redundantly reduce sensory partials into registers
    float4 sn = make_float4(0.f, 0.f, 0.f, 0.f);
    float4 sd = make_float4(0.f, 0.f, 0.f, 0.f);
    #pragma unroll
    for (int qq = 0; qq < 4; ++qq) {
        const float4 a = pnum[qq][j], b = pden[qq][j];
        sn.x += a.x; sn.y += a.y; sn.z += a.z; sn.w += a.w;
        sd.x += b.x; sd.y += b.y; sd.z += b.z; sd.w += b.w;
    }
    __syncthreads();   // pnum/pden reused below

    // ---- 12 ODE unfolds over the compacted, uniformly-padded list ----
    const float4*         __restrict__ pr  = pc    + (q * U4) * N_DIM + j;
    const unsigned short* __restrict__ pi0 = pidxT + j * KMAX + q * U4;

    #pragma unroll 1
    for (int step = 0; step < UNFOLDS; ++step) {
        float m0 = 0.f, m1 = 0.f, m2 = 0.f, m3 = 0.f;
        float d0 = 0.f, d1 = 0.f, d2 = 0.f, d3 = 0.f;

        for (int t = 0; t < U4; t += 8) {
            const u16x8 ix = *(const u16x8*)(pi0 + t);   // 8 pre-shifted offsets
            LTC_BODY(0, ix.s0)
            LTC_BODY(1, ix.s1)
            LTC_BODY(2, ix.s2)
            LTC_BODY(3, ix.s3)
            LTC_BODY(4, ix.s4)
            LTC_BODY(5, ix.s5)
            LTC_BODY(6, ix.s6)
            LTC_BODY(7, ix.s7)
        }

        const float4 vo = v4[j];   // read old v BEFORE the barrier
        pnum[q][j] = make_float4(m0, m1, m2, m3);
        pden[q][j] = make_float4(d0, d1, d2, d3);
        __syncthreads();

        // redundant combine in all q-groups (bitwise-identical results)
        float4 tn = sn, td = sd;
        #pragma unroll
        for (int qq = 0; qq < 4; ++qq) {
            const float4 a = pnum[qq][j], b = pden[qq][j];
            tn.x += a.x; tn.y += a.y; tn.z += a.z; tn.w += a.w;
            td.x += b.x; td.y += b.y; td.z += b.z; td.w += b.w;
        }
        float4 vn;
        vn.x = (fmaf(cmt, vo.x, glv) + tn.x) * FRCP(cg + td.x);
        vn.y = (fmaf(cmt, vo.y, glv) + tn.y) * FRCP(cg + td.y);
        vn.z = (fmaf(cmt, vo.z, glv) + tn.z) * FRCP(cg + td.z);
        vn.w = (fmaf(cmt, vo.w, glv) + tn.w) * FRCP(cg + td.w);
        v4[j] = vn;                // 4 writers, identical bits — benign
        __syncthreads();
    }

    out[(b0 + q) * N_DIM + j] = ((const float*)v4)[(j << 2) + q];
}

extern "C" void kernel_launch(void* const* d_in, const int* in_sizes, int n_in,
                              void* d_out, int out_size, void* d_ws, size_t ws_size,
                              hipStream_t stream)
{
    const float* inputs = (const float*)d_in[0];
    const float* state  = (const float*)d_in[1];
    const float* gleak  = (const float*)d_in[2];
    const float* vleak  = (const float*)d_in[3];
    const float* cm     = (const float*)d_in[4];
    const float* w      = (const float*)d_in[5];
    const float* sigma  = (const float*)d_in[6];
    const float* mu     = (const float*)d_in[7];
    const float* erev   = (const float*)d_in[8];
    const float* sw     = (const float*)d_in[9];
    const float* ssig   = (const float*)d_in[10];
    const float* smu    = (const float*)d_in[11];
    const float* serev  = (const float*)d_in[12];
    const float* mask   = (const float*)d_in[13];
    const float* smask  = (const float*)d_in[14];

    float4* s4 = (float4*)d_ws;                        // [S*N]    = 256 KiB
    float4* pj = s4 + S_DIM * N_DIM;                   // [N]      = 4 KiB
    float4* pc = pj + N_DIM;                           // [KMAX*N] = 1 MiB
    unsigned short* pidxT = (unsigned short*)(pc + KMAX * N_DIM);  // [N][KMAX] = 128 KiB
    int* umax = (int*)(pidxT + N_DIM * KMAX);

    ltc_precompute_s<<<(S_DIM * N_DIM + 255) / 256, 256, 0, stream>>>(
        gleak, vleak, cm, sw, ssig, smu, serev, smask, s4, pj, umax);

    ltc_compact<<<N_DIM, 256, 0, stream>>>(w, sigma, mu, erev, mask, pc, pidxT, umax);

    ltc_main<<<B_TOT / 4, 1024, 0, stream>>>(inputs, state, pc, pidxT, umax,
                                             s4, pj, (float*)d_out);
}